// Round 9
// baseline (242.949 us; speedup 1.0000x reference)
//
#include <hip/hip_runtime.h>
#include <math.h>

typedef unsigned short u16;
typedef unsigned int u32;
typedef __attribute__((ext_vector_type(4))) float f32x4;
typedef __attribute__((ext_vector_type(8))) short short8;
typedef __attribute__((ext_vector_type(4))) unsigned short u16x4;

#define B_DIM 2
#define L_SEQ 4096
#define E_DIM 512
#define NH 8
#define HD 64
#define HID_DIM 2048
#define BL (B_DIM * L_SEQ)

__device__ __forceinline__ float bf2f(u16 u) {
    union { u32 i; float f; } v; v.i = ((u32)u) << 16; return v.f;
}
__device__ __forceinline__ u16 f2bf(float f) {
    union { float f; u32 i; } v; v.f = f;
    u32 r = v.i + 0x7fffu + ((v.i >> 16) & 1u);
    return (u16)(r >> 16);
}

#define GLOAD_LDS16(gp, lp) __builtin_amdgcn_global_load_lds( \
    (const __attribute__((address_space(1))) void*)(gp),      \
    (__attribute__((address_space(3))) void*)(lp), 16, 0, 0)

// ---------------- weight convert + transpose via LDS tiles: f32 [Kd][Nd] -> bf16 [Nd][Kd] ----
__global__ __launch_bounds__(256) void wconv_t(const float* __restrict__ in,
                                               u16* __restrict__ out, int Kd, int Nd) {
    __shared__ u16 t[64][72];
    const int k0 = blockIdx.y * 64, n0 = blockIdx.x * 64;
    const int tid = threadIdx.x;
    const int col4 = tid & 15;
    const int rowb = tid >> 4;
#pragma unroll
    for (int i = 0; i < 4; ++i) {
        const int k = rowb + i * 16;
        const float4 v = *(const float4*)(in + (size_t)(k0 + k) * Nd + n0 + col4 * 4);
        t[col4 * 4 + 0][k] = f2bf(v.x);
        t[col4 * 4 + 1][k] = f2bf(v.y);
        t[col4 * 4 + 2][k] = f2bf(v.z);
        t[col4 * 4 + 3][k] = f2bf(v.w);
    }
    __syncthreads();
    const int n = tid >> 2, ch = tid & 3;
    u16* dst = out + (size_t)(n0 + n) * Kd + k0 + ch * 16;
    *(short8*)(dst) = *(const short8*)&t[n][ch * 16];
    *(short8*)(dst + 8) = *(const short8*)&t[n][ch * 16 + 8];
}

// ---------------- LayerNorm: f32 [rows][512] -> bf16 [rows][512], wave per row ----------------
__global__ __launch_bounds__(256) void ln_kernel(const float* __restrict__ x,
                                                 const float* __restrict__ g,
                                                 const float* __restrict__ b,
                                                 u16* __restrict__ out) {
    const int row = blockIdx.x * 4 + (threadIdx.x >> 6);
    const int lane = threadIdx.x & 63;
    const float4* xr = (const float4*)(x + (size_t)row * E_DIM);
    const float4 v0 = xr[lane];
    const float4 v1 = xr[lane + 64];
    float s  = v0.x + v0.y + v0.z + v0.w + v1.x + v1.y + v1.z + v1.w;
    float s2 = v0.x*v0.x + v0.y*v0.y + v0.z*v0.z + v0.w*v0.w
             + v1.x*v1.x + v1.y*v1.y + v1.z*v1.z + v1.w*v1.w;
#pragma unroll
    for (int off = 32; off > 0; off >>= 1) {
        s  += __shfl_xor(s, off);
        s2 += __shfl_xor(s2, off);
    }
    const float mu = s * (1.f / E_DIM);
    const float rs = rsqrtf(s2 * (1.f / E_DIM) - mu * mu + 1e-5f);
    const float4 g0 = ((const float4*)g)[lane], g1 = ((const float4*)g)[lane + 64];
    const float4 b0 = ((const float4*)b)[lane], b1 = ((const float4*)b)[lane + 64];
    u16x4 o0, o1;
    o0.x = f2bf((v0.x - mu) * rs * g0.x + b0.x);
    o0.y = f2bf((v0.y - mu) * rs * g0.y + b0.y);
    o0.z = f2bf((v0.z - mu) * rs * g0.z + b0.z);
    o0.w = f2bf((v0.w - mu) * rs * g0.w + b0.w);
    o1.x = f2bf((v1.x - mu) * rs * g1.x + b1.x);
    o1.y = f2bf((v1.y - mu) * rs * g1.y + b1.y);
    o1.z = f2bf((v1.z - mu) * rs * g1.z + b1.z);
    o1.w = f2bf((v1.w - mu) * rs * g1.w + b1.w);
    u16x4* orow = (u16x4*)(out + (size_t)row * E_DIM);
    orow[lane] = o0;
    orow[lane + 64] = o1;
}

// ---------------- GEMM: C[M][N] = A[M][K](bf16) @ Bt[N][K](bf16) + bias (+gelu) (+res) -------
// BARRIER-FREE K-loop (round 7 concept, round 8 tail fix). 128x128 block, 4 waves (2x2),
// BK=32. Each wave stages its OWN A-half + B-half into a private 16KB LDS region (2-buffer
// ring) via global_load_lds -- no cross-wave LDS sharing, NO s_barrier in the loop.
// Per-wave sync: vmcnt(8) at loop top in steady state (tile t landed, t+1 in flight);
// *** vmcnt(0) on the peeled LAST tile (r8 fix: at t=NT-1 only 8 loads are outstanding, so
// vmcnt(8) passed immediately and read un-landed LDS -> absmax 0.51). ***
// lgkmcnt(0)+sched_barrier after frag reads so the D=2 overwrite can't land early.
template<int K_T, bool RES, bool GELU, bool OUTBF>
__global__ __launch_bounds__(256) void gemm_bt(const u16* __restrict__ A,
                                               const u16* __restrict__ Bt,
                                               const float* __restrict__ bias,
                                               const float* __restrict__ res,
                                               void* __restrict__ Cp,
                                               int M, int N, int nbx) {
    constexpr int K = K_T;
    constexpr int NT = K / 32;
    __shared__ u16 sb[4 * 8192];            // 4 waves x 16KB (2 bufs x 8KB)
    const int tid = threadIdx.x;
    const int wave = tid >> 6, lane = tid & 63;
    const int wr = wave >> 1, wc = wave & 1;

    const int xcd = blockIdx.x & 7;
    const int q = blockIdx.x >> 3;
    const int bx = q % nbx;
    const int by = (q / nbx) * 8 + xcd;
    const int bm = by * 128, bn = bx * 128;

    f32x4 acc[4][4];
#pragma unroll
    for (int m = 0; m < 4; ++m)
#pragma unroll
        for (int n = 0; n < 4; ++n) acc[m][n] = 0.f;

    const int sr = lane & 15;
    const int sg = lane >> 4;
    const u16* gA = A + (size_t)(bm + wr * 64 + sr) * K + sg * 8;
    const u16* gB = Bt + (size_t)(bn + wc * 64 + sr) * K + sg * 8;
    u16* reg0 = sb + wave * 8192;

    auto stage = [&](int t) {
        const int k0 = t * 32;
        u16* dst = reg0 + (t & 1) * 4096;
#pragma unroll
        for (int h = 0; h < 4; ++h)
            GLOAD_LDS16(gA + (size_t)h * 16 * K + k0, dst + h * 512);
#pragma unroll
        for (int h = 0; h < 4; ++h)
            GLOAD_LDS16(gB + (size_t)h * 16 * K + k0, dst + 2048 + h * 512);
    };

    auto mfma_tile = [&](const u16* src) {
        short8 af[4], bfr[4];
#pragma unroll
        for (int m = 0; m < 4; ++m)
            af[m] = *(const short8*)&src[m * 512 + lane * 8];
#pragma unroll
        for (int n = 0; n < 4; ++n)
            bfr[n] = *(const short8*)&src[2048 + n * 512 + lane * 8];
        asm volatile("s_waitcnt lgkmcnt(0)" ::: "memory"); // reads done before overwrite
        __builtin_amdgcn_sched_barrier(0);
        return (void)0, (af[0], bfr[0]), [&]() {};         // (unused; kept simple below)
    };
    (void)mfma_tile;

    stage(0);
    stage(1);
#pragma unroll 2
    for (int t = 0; t < NT - 1; ++t) {
        asm volatile("s_waitcnt vmcnt(8)" ::: "memory");   // tile t landed (t+1 in flight)
        const u16* src = reg0 + (t & 1) * 4096;
        short8 af[4], bfr[4];
#pragma unroll
        for (int m = 0; m < 4; ++m)
            af[m] = *(const short8*)&src[m * 512 + lane * 8];
#pragma unroll
        for (int n = 0; n < 4; ++n)
            bfr[n] = *(const short8*)&src[2048 + n * 512 + lane * 8];
        asm volatile("s_waitcnt lgkmcnt(0)" ::: "memory"); // reads done before overwrite
        __builtin_amdgcn_sched_barrier(0);
        if (t + 2 < NT) stage(t + 2);                      // refills buf (t&1)
        __builtin_amdgcn_s_setprio(1);
#pragma unroll
        for (int m = 0; m < 4; ++m)
#pragma unroll
            for (int n = 0; n < 4; ++n)
                acc[m][n] = __builtin_amdgcn_mfma_f32_16x16x32_bf16(af[m], bfr[n], acc[m][n], 0, 0, 0);
        __builtin_amdgcn_s_setprio(0);
    }
    {   // peeled last tile: nothing else in flight -> must drain fully (r8 fix)
        constexpr int t = NT - 1;
        asm volatile("s_waitcnt vmcnt(0)" ::: "memory");
        const u16* src = reg0 + (t & 1) * 4096;
        short8 af[4], bfr[4];
#pragma unroll
        for (int m = 0; m < 4; ++m)
            af[m] = *(const short8*)&src[m * 512 + lane * 8];
#pragma unroll
        for (int n = 0; n < 4; ++n)
            bfr[n] = *(const short8*)&src[2048 + n * 512 + lane * 8];
        __builtin_amdgcn_s_setprio(1);
#pragma unroll
        for (int m = 0; m < 4; ++m)
#pragma unroll
            for (int n = 0; n < 4; ++n)
                acc[m][n] = __builtin_amdgcn_mfma_f32_16x16x32_bf16(af[m], bfr[n], acc[m][n], 0, 0, 0);
        __builtin_amdgcn_s_setprio(0);
    }

    const int ccol = lane & 15;
    const int crow = (lane >> 4) * 4;
#pragma unroll
    for (int n = 0; n < 4; ++n) {
        const int gc = bn + wc * 64 + n * 16 + ccol;
        const float bi = bias[gc];
#pragma unroll
        for (int m = 0; m < 4; ++m) {
            const int gr0 = bm + wr * 64 + m * 16 + crow;
#pragma unroll
            for (int j = 0; j < 4; ++j) {
                float v = acc[m][n][j] + bi;
                if (GELU) v = 0.5f * v * (1.f + erff(v * 0.70710678118f));
                const size_t idx = (size_t)(gr0 + j) * N + gc;
                if (RES) v += res[idx];
                if (OUTBF) ((u16*)Cp)[idx] = f2bf(v);
                else       ((float*)Cp)[idx] = v;
            }
        }
    }
}

// ---------------- dilated attention via parity split -> dense sliding-window flash attn ------
__global__ __launch_bounds__(256) void attn_mfma(const u16* __restrict__ qkv,
                                                 u16* __restrict__ o) {
    __shared__ u16 K_lds[32 * 64];
    __shared__ u16 V_lds[32 * 64];
    const int tid = threadIdx.x;
    const int w = tid >> 6, lane = tid & 63;
    const int g = lane >> 4, q = lane & 15;
    const int qt = blockIdx.x, bph = blockIdx.y;
    const int b = bph >> 4, p = (bph >> 3) & 1, h = bph & 7;
    const int q0 = qt * 64;

    const size_t rowstride = 3 * E_DIM;
    const u16* qbase = qkv + (size_t)b * L_SEQ * rowstride + h * HD;

    const int qmin = q0 + w * 16, qmax = qmin + 15;
    const int qs_lane = qmin + q;
    const int qi = 2 * qs_lane + p;

    short8 qfrag[2];
    qfrag[0] = *(const short8*)(qbase + (size_t)qi * rowstride + g * 8);
    qfrag[1] = *(const short8*)(qbase + (size_t)qi * rowstride + 32 + g * 8);

    f32x4 oacc[4];
#pragma unroll
    for (int dt = 0; dt < 4; ++dt) oacc[dt] = 0.f;
    float m = -1e30f, l = 0.f;

    for (int s = 0; s < 6; ++s) {
        const int ks0 = q0 - 128 + 32 * s;
        if (ks0 >= 0) {
            const int r = 8 * w + (lane >> 3);
            const int gr = lane & 7;
            const size_t krow = (size_t)(2 * (ks0 + r) + p) * rowstride;
            const u16* ksrc = qbase + krow + E_DIM + 8 * (gr ^ (r & 7));
            const u16* vsrc = qbase + krow + 2 * E_DIM + 8 * gr;
            GLOAD_LDS16(ksrc, &K_lds[w * 512]);
            GLOAD_LDS16(vsrc, &V_lds[w * 512]);
        }
        __syncthreads();
        const bool active = (ks0 >= 0) && (ks0 <= qmax) && (ks0 + 31 >= qmin - 128);
        if (active) {
            f32x4 st[2];
            st[0] = 0.f; st[1] = 0.f;
#pragma unroll
            for (int t = 0; t < 2; ++t) {
#pragma unroll
                for (int c = 0; c < 2; ++c) {
                    const int kk = t * 16 + q;
                    const int gs = (c * 4 + g) ^ (kk & 7);
                    short8 kf = *(const short8*)&K_lds[kk * 64 + gs * 8];
                    st[t] = __builtin_amdgcn_mfma_f32_16x16x32_bf16(kf, qfrag[c], st[t], 0, 0, 0);
                }
            }
            float sv[2][4];
            float bm = -3.0e38f;
#pragma unroll
            for (int t = 0; t < 2; ++t)
#pragma unroll
                for (int j = 0; j < 4; ++j) {
                    const int kk = ks0 + t * 16 + 4 * g + j;
                    float x = st[t][j] * 0.125f;
                    const bool ok = (kk <= qs_lane) && (qs_lane - kk <= 128);
                    x = ok ? x : -3.0e38f;
                    sv[t][j] = x;
                    bm = fmaxf(bm, x);
                }
            bm = fmaxf(bm, __shfl_xor(bm, 16));
            bm = fmaxf(bm, __shfl_xor(bm, 32));
            const float mn = fmaxf(m, bm);
            const float sc = __expf(m - mn);
            m = mn;
            float rs = 0.f;
            u32 pk[2][2];
#pragma unroll
            for (int t = 0; t < 2; ++t) {
                const float e0 = __expf(sv[t][0] - mn), e1 = __expf(sv[t][1] - mn);
                const float e2 = __expf(sv[t][2] - mn), e3 = __expf(sv[t][3] - mn);
                rs += (e0 + e1) + (e2 + e3);
                pk[t][0] = (u32)f2bf(e0) | ((u32)f2bf(e1) << 16);
                pk[t][1] = (u32)f2bf(e2) | ((u32)f2bf(e3) << 16);
            }
            rs += __shfl_xor(rs, 16);
            rs += __shfl_xor(rs, 32);
            l = l * sc + rs;
#pragma unroll
            for (int dt = 0; dt < 4; ++dt) oacc[dt] *= sc;
            union { u32 w4[4]; short8 s8; } bfr;
#pragma unroll
            for (int r = 0; r < 4; ++r) {
                const int src = (((g << 1) + (r >> 1)) & 3) * 16 + q;
                const int w0 = __shfl((int)pk[0][r & 1], src);
                const int w1 = __shfl((int)pk[1][r & 1], src);
                bfr.w4[r] = (g & 2) ? (u32)w1 : (u32)w0;
            }
#pragma unroll
            for (int dt = 0; dt < 4; ++dt) {
                union { u16 h8[8]; short8 s8; } vf;
#pragma unroll
                for (int e = 0; e < 8; ++e)
                    vf.h8[e] = V_lds[(8 * g + e) * 64 + dt * 16 + q];
                oacc[dt] = __builtin_amdgcn_mfma_f32_16x16x32_bf16(vf.s8, bfr.s8, oacc[dt], 0, 0, 0);
            }
        }
        __syncthreads();
    }
    const float inv = 1.f / l;
    u16* obase = o + ((size_t)b * L_SEQ + (size_t)qi) * E_DIM + h * HD;
#pragma unroll
    for (int dt = 0; dt < 4; ++dt) {
        u16x4 pkd;
        pkd.x = f2bf(oacc[dt][0] * inv);
        pkd.y = f2bf(oacc[dt][1] * inv);
        pkd.z = f2bf(oacc[dt][2] * inv);
        pkd.w = f2bf(oacc[dt][3] * inv);
        *(u16x4*)(obase + dt * 16 + 4 * g) = pkd;
    }
}

// --------------------------------------------------------------------------------------------
extern "C" void kernel_launch(void* const* d_in, const int* in_sizes, int n_in,
                              void* d_out, int out_size, void* d_ws, size_t ws_size,
                              hipStream_t stream) {
    const float* x    = (const float*)d_in[0];
    const float* ln1g = (const float*)d_in[1];
    const float* ln1b = (const float*)d_in[2];
    const float* qkvw = (const float*)d_in[3];
    const float* qkvb = (const float*)d_in[4];
    const float* outw = (const float*)d_in[5];
    const float* outb = (const float*)d_in[6];
    const float* ln2g = (const float*)d_in[7];
    const float* ln2b = (const float*)d_in[8];
    const float* w1   = (const float*)d_in[9];
    const float* b1   = (const float*)d_in[10];
    const float* w2   = (const float*)d_in[11];
    const float* b2   = (const float*)d_in[12];
    float* outp = (float*)d_out;

    char* ws = (char*)d_ws;
    size_t off = 0;
    auto alloc = [&](size_t bytes) {
        void* p = ws + off;
        off += (bytes + 255) & ~(size_t)255;
        return p;
    };
    u16*   hbuf  = (u16*)  alloc((size_t)BL * E_DIM * 2);
    u16*   qkvB  = (u16*)  alloc((size_t)BL * 3 * E_DIM * 2);
    u16*   obuf  = (u16*)  alloc((size_t)BL * E_DIM * 2);
    float* x2    = (float*)alloc((size_t)BL * E_DIM * 4);
    u16*   h2    = (u16*)  alloc((size_t)BL * E_DIM * 2);
    u16*   g1    = (u16*)  alloc((size_t)BL * HID_DIM * 2);
    u16*   wqkvT = (u16*)  alloc((size_t)3 * E_DIM * E_DIM * 2);
    u16*   woutT = (u16*)  alloc((size_t)E_DIM * E_DIM * 2);
    u16*   w1T   = (u16*)  alloc((size_t)HID_DIM * E_DIM * 2);
    u16*   w2T   = (u16*)  alloc((size_t)E_DIM * HID_DIM * 2);

    wconv_t<<<dim3((3 * E_DIM) / 64, E_DIM / 64), 256, 0, stream>>>(qkvw, wqkvT, E_DIM, 3 * E_DIM);
    wconv_t<<<dim3(E_DIM / 64, E_DIM / 64), 256, 0, stream>>>(outw, woutT, E_DIM, E_DIM);
    wconv_t<<<dim3(HID_DIM / 64, E_DIM / 64), 256, 0, stream>>>(w1, w1T, E_DIM, HID_DIM);
    wconv_t<<<dim3(E_DIM / 64, HID_DIM / 64), 256, 0, stream>>>(w2, w2T, HID_DIM, E_DIM);

    ln_kernel<<<BL / 4, 256, 0, stream>>>(x, ln1g, ln1b, hbuf);
    gemm_bt<E_DIM, false, false, true><<<(BL / 128) * 12, 256, 0, stream>>>(
        hbuf, wqkvT, qkvb, nullptr, qkvB, BL, 3 * E_DIM, 12);
    attn_mfma<<<dim3(32, 32), 256, 0, stream>>>(qkvB, obuf);
    gemm_bt<E_DIM, true, false, false><<<(BL / 128) * 4, 256, 0, stream>>>(
        obuf, woutT, outb, x, x2, BL, E_DIM, 4);
    ln_kernel<<<BL / 4, 256, 0, stream>>>(x2, ln2g, ln2b, h2);
    gemm_bt<E_DIM, false, true, true><<<(BL / 128) * 16, 256, 0, stream>>>(
        h2, w1T, b1, nullptr, g1, BL, HID_DIM, 16);
    gemm_bt<HID_DIM, true, false, false><<<(BL / 128) * 4, 256, 0, stream>>>(
        g1, w2T, b2, x2, outp, BL, E_DIM, 4);
}

// Round 10
// 156.622 us; speedup vs baseline: 1.5512x; 1.5512x over previous
//
#include <hip/hip_runtime.h>
#include <math.h>

typedef unsigned short u16;
typedef unsigned int u32;
typedef __attribute__((ext_vector_type(4))) float f32x4;
typedef __attribute__((ext_vector_type(8))) short short8;
typedef __attribute__((ext_vector_type(4))) unsigned short u16x4;

#define B_DIM 2
#define L_SEQ 4096
#define E_DIM 512
#define NH 8
#define HD 64
#define HID_DIM 2048
#define BL (B_DIM * L_SEQ)

__device__ __forceinline__ float bf2f(u16 u) {
    union { u32 i; float f; } v; v.i = ((u32)u) << 16; return v.f;
}
__device__ __forceinline__ u16 f2bf(float f) {
    union { float f; u32 i; } v; v.f = f;
    u32 r = v.i + 0x7fffu + ((v.i >> 16) & 1u);
    return (u16)(r >> 16);
}
__device__ __forceinline__ float gelu_f(float v) {
    // tanh-form gelu; 0.5*(1+tanh(y)) = t/(t+1), t=e^{2y}. Clamp for inf-safety.
    float y = fminf(0.7978845608f * (v + 0.044715f * v * v * v), 15.f);
    float t = __expf(2.f * y);
    return v * (t / (t + 1.f));
}

#define GLOAD_LDS16(gp, lp) __builtin_amdgcn_global_load_lds( \
    (const __attribute__((address_space(1))) void*)(gp),      \
    (__attribute__((address_space(3))) void*)(lp), 16, 0, 0)

template<int VM> __device__ __forceinline__ void waitvm() {
    asm volatile("s_waitcnt vmcnt(%0)" :: "n"(VM) : "memory");
}

// ---------------- weight convert + transpose via LDS tiles: f32 [Kd][Nd] -> bf16 [Nd][Kd] ----
__global__ __launch_bounds__(256) void wconv_t(const float* __restrict__ in,
                                               u16* __restrict__ out, int Kd, int Nd) {
    __shared__ u16 t[64][72];
    const int k0 = blockIdx.y * 64, n0 = blockIdx.x * 64;
    const int tid = threadIdx.x;
    const int col4 = tid & 15;
    const int rowb = tid >> 4;
#pragma unroll
    for (int i = 0; i < 4; ++i) {
        const int k = rowb + i * 16;
        const float4 v = *(const float4*)(in + (size_t)(k0 + k) * Nd + n0 + col4 * 4);
        t[col4 * 4 + 0][k] = f2bf(v.x);
        t[col4 * 4 + 1][k] = f2bf(v.y);
        t[col4 * 4 + 2][k] = f2bf(v.z);
        t[col4 * 4 + 3][k] = f2bf(v.w);
    }
    __syncthreads();
    const int n = tid >> 2, ch = tid & 3;
    u16* dst = out + (size_t)(n0 + n) * Kd + k0 + ch * 16;
    *(short8*)(dst) = *(const short8*)&t[n][ch * 16];
    *(short8*)(dst + 8) = *(const short8*)&t[n][ch * 16 + 8];
}

// ---------------- LayerNorm: f32 [rows][512] -> bf16 [rows][512], wave per row ----------------
__global__ __launch_bounds__(256) void ln_kernel(const float* __restrict__ x,
                                                 const float* __restrict__ g,
                                                 const float* __restrict__ b,
                                                 u16* __restrict__ out) {
    const int row = blockIdx.x * 4 + (threadIdx.x >> 6);
    const int lane = threadIdx.x & 63;
    const float4* xr = (const float4*)(x + (size_t)row * E_DIM);
    const float4 v0 = xr[lane];
    const float4 v1 = xr[lane + 64];
    float s  = v0.x + v0.y + v0.z + v0.w + v1.x + v1.y + v1.z + v1.w;
    float s2 = v0.x*v0.x + v0.y*v0.y + v0.z*v0.z + v0.w*v0.w
             + v1.x*v1.x + v1.y*v1.y + v1.z*v1.z + v1.w*v1.w;
#pragma unroll
    for (int off = 32; off > 0; off >>= 1) {
        s  += __shfl_xor(s, off);
        s2 += __shfl_xor(s2, off);
    }
    const float mu = s * (1.f / E_DIM);
    const float rs = rsqrtf(s2 * (1.f / E_DIM) - mu * mu + 1e-5f);
    const float4 g0 = ((const float4*)g)[lane], g1 = ((const float4*)g)[lane + 64];
    const float4 b0 = ((const float4*)b)[lane], b1 = ((const float4*)b)[lane + 64];
    u16x4 o0, o1;
    o0.x = f2bf((v0.x - mu) * rs * g0.x + b0.x);
    o0.y = f2bf((v0.y - mu) * rs * g0.y + b0.y);
    o0.z = f2bf((v0.z - mu) * rs * g0.z + b0.z);
    o0.w = f2bf((v0.w - mu) * rs * g0.w + b0.w);
    o1.x = f2bf((v1.x - mu) * rs * g1.x + b1.x);
    o1.y = f2bf((v1.y - mu) * rs * g1.y + b1.y);
    o1.z = f2bf((v1.z - mu) * rs * g1.z + b1.z);
    o1.w = f2bf((v1.w - mu) * rs * g1.w + b1.w);
    u16x4* orow = (u16x4*)(out + (size_t)row * E_DIM);
    orow[lane] = o0;
    orow[lane + 64] = o1;
}

// ---------------- GEMM: C[M][N] = A[M][K](bf16) @ Bt[N][K](bf16) + bias (+gelu) (+res) -------
// Round 9 finding: time = staged-volume / ~7.2 TB/s, invariant to schedule. So: minimize
// volume. 8 waves (2x4), BM=128, BN=128 or 256. r5-proven counted-vmcnt skeleton, 3-buffer
// depth-2: per step t: stage(t+2) -> vmcnt(2L) -> barrier -> compute(t) -> barrier.
// L = loads/wave/tile = (128+BN)/128 (2 or 3). Tail peels vmcnt(L), vmcnt(0).
// LDS: 3 x (128+BN)*64B = 48/72KB -> 3 or 2 blocks/CU. Conflict-free LDS layout as before.
template<int K_T, int BN_T, bool RES, bool GELU, bool OUTBF>
__global__ __launch_bounds__(512) void gemm_bt(const u16* __restrict__ A,
                                               const u16* __restrict__ Bt,
                                               const float* __restrict__ bias,
                                               const float* __restrict__ res,
                                               void* __restrict__ Cp,
                                               int M, int N, int nbx) {
    constexpr int K = K_T;
    constexpr int NT = K / 32;                 // >= 3
    constexpr int NR = BN_T / 64;              // B frags per wave (2 or 4), MR = 4
    constexpr int BPW = BN_T / 128;            // B gloads per wave (1 or 2); A gloads = 1
    constexpr int L = 1 + BPW;                 // loads per wave per tile
    constexpr int AU = 128 * 32;               // 4096 u16
    constexpr int BU = BN_T * 32;
    constexpr int TILE_U = AU + BU;
    __shared__ u16 sb[3 * TILE_U];
    const int tid = threadIdx.x;
    const int wave = tid >> 6, lane = tid & 63;
    const int wr = wave >> 2, wc = wave & 3;   // 2 x 4 wave grid

    const int xcd = blockIdx.x & 7;
    const int q = blockIdx.x >> 3;
    const int bx = q % nbx;
    const int by = (q / nbx) * 8 + xcd;
    const int bm = by * 128, bn = bx * BN_T;

    f32x4 acc[4][NR];
#pragma unroll
    for (int m = 0; m < 4; ++m)
#pragma unroll
        for (int n = 0; n < NR; ++n) acc[m][n] = 0.f;

    const int sr = lane & 15;
    const int sg = lane >> 4;
    const u16* gA = A + (size_t)(bm + wave * 16 + sr) * K + sg * 8;
    const u16* gB = Bt + (size_t)(bn + sr) * K + sg * 8;

    auto stage = [&](int buf, int t) {
        const int k0 = t * 32;
        u16* dst = sb + buf * TILE_U;
        GLOAD_LDS16(gA + k0, dst + wave * 512);
#pragma unroll
        for (int h = 0; h < BPW; ++h) {
            const int G = wave * BPW + h;
            GLOAD_LDS16(gB + (size_t)G * 16 * K + k0, dst + AU + G * 512);
        }
    };

    auto compute = [&](int buf) {
        const u16* src = sb + buf * TILE_U;
        short8 af[4], bfr[NR];
#pragma unroll
        for (int m = 0; m < 4; ++m)
            af[m] = *(const short8*)&src[(wr * 4 + m) * 512 + lane * 8];
#pragma unroll
        for (int n = 0; n < NR; ++n)
            bfr[n] = *(const short8*)&src[AU + (wc * NR + n) * 512 + lane * 8];
        __builtin_amdgcn_s_setprio(1);
#pragma unroll
        for (int m = 0; m < 4; ++m)
#pragma unroll
            for (int n = 0; n < NR; ++n)
                acc[m][n] = __builtin_amdgcn_mfma_f32_16x16x32_bf16(af[m], bfr[n], acc[m][n], 0, 0, 0);
        __builtin_amdgcn_s_setprio(0);
    };

    stage(0, 0);
    stage(1, 1);
    int sbuf = 2, cbuf = 0;
    for (int t = 0; t < NT - 2; ++t) {
        stage(sbuf, t + 2);
        sbuf = (sbuf == 2) ? 0 : sbuf + 1;
        waitvm<2 * L>();                       // tile t landed; t+1, t+2 in flight
        __builtin_amdgcn_s_barrier();
        compute(cbuf);
        cbuf = (cbuf == 2) ? 0 : cbuf + 1;
        __builtin_amdgcn_s_barrier();
    }
    waitvm<L>();                               // tile NT-2 landed; NT-1 in flight
    __builtin_amdgcn_s_barrier();
    compute(cbuf);
    cbuf = (cbuf == 2) ? 0 : cbuf + 1;
    __builtin_amdgcn_s_barrier();
    waitvm<0>();                               // last tile: full drain (r8 lesson)
    __builtin_amdgcn_s_barrier();
    compute(cbuf);

    const int ccol = lane & 15;
    const int crow = (lane >> 4) * 4;
#pragma unroll
    for (int n = 0; n < NR; ++n) {
        const int gc = bn + wc * (NR * 16) + n * 16 + ccol;
        const float bi = bias[gc];
#pragma unroll
        for (int m = 0; m < 4; ++m) {
            const int gr0 = bm + wr * 64 + m * 16 + crow;
#pragma unroll
            for (int j = 0; j < 4; ++j) {
                float v = acc[m][n][j] + bi;
                if (GELU) v = gelu_f(v);
                const size_t idx = (size_t)(gr0 + j) * N + gc;
                if (RES) v += res[idx];
                if (OUTBF) ((u16*)Cp)[idx] = f2bf(v);
                else       ((float*)Cp)[idx] = v;
            }
        }
    }
}

// ---------------- dilated attention via parity split -> dense sliding-window flash attn ------
__global__ __launch_bounds__(256) void attn_mfma(const u16* __restrict__ qkv,
                                                 u16* __restrict__ o) {
    __shared__ u16 K_lds[32 * 64];
    __shared__ u16 V_lds[32 * 64];
    const int tid = threadIdx.x;
    const int w = tid >> 6, lane = tid & 63;
    const int g = lane >> 4, q = lane & 15;
    const int qt = blockIdx.x, bph = blockIdx.y;
    const int b = bph >> 4, p = (bph >> 3) & 1, h = bph & 7;
    const int q0 = qt * 64;

    const size_t rowstride = 3 * E_DIM;
    const u16* qbase = qkv + (size_t)b * L_SEQ * rowstride + h * HD;

    const int qmin = q0 + w * 16, qmax = qmin + 15;
    const int qs_lane = qmin + q;
    const int qi = 2 * qs_lane + p;

    short8 qfrag[2];
    qfrag[0] = *(const short8*)(qbase + (size_t)qi * rowstride + g * 8);
    qfrag[1] = *(const short8*)(qbase + (size_t)qi * rowstride + 32 + g * 8);

    f32x4 oacc[4];
#pragma unroll
    for (int dt = 0; dt < 4; ++dt) oacc[dt] = 0.f;
    float m = -1e30f, l = 0.f;

    for (int s = 0; s < 6; ++s) {
        const int ks0 = q0 - 128 + 32 * s;
        if (ks0 >= 0) {
            const int r = 8 * w + (lane >> 3);
            const int gr = lane & 7;
            const size_t krow = (size_t)(2 * (ks0 + r) + p) * rowstride;
            const u16* ksrc = qbase + krow + E_DIM + 8 * (gr ^ (r & 7));
            const u16* vsrc = qbase + krow + 2 * E_DIM + 8 * gr;
            GLOAD_LDS16(ksrc, &K_lds[w * 512]);
            GLOAD_LDS16(vsrc, &V_lds[w * 512]);
        }
        __syncthreads();
        const bool active = (ks0 >= 0) && (ks0 <= qmax) && (ks0 + 31 >= qmin - 128);
        if (active) {
            f32x4 st[2];
            st[0] = 0.f; st[1] = 0.f;
#pragma unroll
            for (int t = 0; t < 2; ++t) {
#pragma unroll
                for (int c = 0; c < 2; ++c) {
                    const int kk = t * 16 + q;
                    const int gs = (c * 4 + g) ^ (kk & 7);
                    short8 kf = *(const short8*)&K_lds[kk * 64 + gs * 8];
                    st[t] = __builtin_amdgcn_mfma_f32_16x16x32_bf16(kf, qfrag[c], st[t], 0, 0, 0);
                }
            }
            float sv[2][4];
            float bm = -3.0e38f;
#pragma unroll
            for (int t = 0; t < 2; ++t)
#pragma unroll
                for (int j = 0; j < 4; ++j) {
                    const int kk = ks0 + t * 16 + 4 * g + j;
                    float x = st[t][j] * 0.125f;
                    const bool ok = (kk <= qs_lane) && (qs_lane - kk <= 128);
                    x = ok ? x : -3.0e38f;
                    sv[t][j] = x;
                    bm = fmaxf(bm, x);
                }
            bm = fmaxf(bm, __shfl_xor(bm, 16));
            bm = fmaxf(bm, __shfl_xor(bm, 32));
            const float mn = fmaxf(m, bm);
            const float sc = __expf(m - mn);
            m = mn;
            float rs = 0.f;
            u32 pk[2][2];
#pragma unroll
            for (int t = 0; t < 2; ++t) {
                const float e0 = __expf(sv[t][0] - mn), e1 = __expf(sv[t][1] - mn);
                const float e2 = __expf(sv[t][2] - mn), e3 = __expf(sv[t][3] - mn);
                rs += (e0 + e1) + (e2 + e3);
                pk[t][0] = (u32)f2bf(e0) | ((u32)f2bf(e1) << 16);
                pk[t][1] = (u32)f2bf(e2) | ((u32)f2bf(e3) << 16);
            }
            rs += __shfl_xor(rs, 16);
            rs += __shfl_xor(rs, 32);
            l = l * sc + rs;
#pragma unroll
            for (int dt = 0; dt < 4; ++dt) oacc[dt] *= sc;
            union { u32 w4[4]; short8 s8; } bfr;
#pragma unroll
            for (int r = 0; r < 4; ++r) {
                const int src = (((g << 1) + (r >> 1)) & 3) * 16 + q;
                const int w0 = __shfl((int)pk[0][r & 1], src);
                const int w1 = __shfl((int)pk[1][r & 1], src);
                bfr.w4[r] = (g & 2) ? (u32)w1 : (u32)w0;
            }
#pragma unroll
            for (int dt = 0; dt < 4; ++dt) {
                union { u16 h8[8]; short8 s8; } vf;
#pragma unroll
                for (int e = 0; e < 8; ++e)
                    vf.h8[e] = V_lds[(8 * g + e) * 64 + dt * 16 + q];
                oacc[dt] = __builtin_amdgcn_mfma_f32_16x16x32_bf16(vf.s8, bfr.s8, oacc[dt], 0, 0, 0);
            }
        }
        __syncthreads();
    }
    const float inv = 1.f / l;
    u16* obase = o + ((size_t)b * L_SEQ + (size_t)qi) * E_DIM + h * HD;
#pragma unroll
    for (int dt = 0; dt < 4; ++dt) {
        u16x4 pkd;
        pkd.x = f2bf(oacc[dt][0] * inv);
        pkd.y = f2bf(oacc[dt][1] * inv);
        pkd.z = f2bf(oacc[dt][2] * inv);
        pkd.w = f2bf(oacc[dt][3] * inv);
        *(u16x4*)(obase + dt * 16 + 4 * g) = pkd;
    }
}

// --------------------------------------------------------------------------------------------
extern "C" void kernel_launch(void* const* d_in, const int* in_sizes, int n_in,
                              void* d_out, int out_size, void* d_ws, size_t ws_size,
                              hipStream_t stream) {
    const float* x    = (const float*)d_in[0];
    const float* ln1g = (const float*)d_in[1];
    const float* ln1b = (const float*)d_in[2];
    const float* qkvw = (const float*)d_in[3];
    const float* qkvb = (const float*)d_in[4];
    const float* outw = (const float*)d_in[5];
    const float* outb = (const float*)d_in[6];
    const float* ln2g = (const float*)d_in[7];
    const float* ln2b = (const float*)d_in[8];
    const float* w1   = (const float*)d_in[9];
    const float* b1   = (const float*)d_in[10];
    const float* w2   = (const float*)d_in[11];
    const float* b2   = (const float*)d_in[12];
    float* outp = (float*)d_out;

    char* ws = (char*)d_ws;
    size_t off = 0;
    auto alloc = [&](size_t bytes) {
        void* p = ws + off;
        off += (bytes + 255) & ~(size_t)255;
        return p;
    };
    u16*   hbuf  = (u16*)  alloc((size_t)BL * E_DIM * 2);
    u16*   qkvB  = (u16*)  alloc((size_t)BL * 3 * E_DIM * 2);
    u16*   obuf  = (u16*)  alloc((size_t)BL * E_DIM * 2);
    float* x2    = (float*)alloc((size_t)BL * E_DIM * 4);
    u16*   h2    = (u16*)  alloc((size_t)BL * E_DIM * 2);
    u16*   g1    = (u16*)  alloc((size_t)BL * HID_DIM * 2);
    u16*   wqkvT = (u16*)  alloc((size_t)3 * E_DIM * E_DIM * 2);
    u16*   woutT = (u16*)  alloc((size_t)E_DIM * E_DIM * 2);
    u16*   w1T   = (u16*)  alloc((size_t)HID_DIM * E_DIM * 2);
    u16*   w2T   = (u16*)  alloc((size_t)E_DIM * HID_DIM * 2);

    wconv_t<<<dim3((3 * E_DIM) / 64, E_DIM / 64), 256, 0, stream>>>(qkvw, wqkvT, E_DIM, 3 * E_DIM);
    wconv_t<<<dim3(E_DIM / 64, E_DIM / 64), 256, 0, stream>>>(outw, woutT, E_DIM, E_DIM);
    wconv_t<<<dim3(HID_DIM / 64, E_DIM / 64), 256, 0, stream>>>(w1, w1T, E_DIM, HID_DIM);
    wconv_t<<<dim3(E_DIM / 64, HID_DIM / 64), 256, 0, stream>>>(w2, w2T, HID_DIM, E_DIM);

    ln_kernel<<<BL / 4, 256, 0, stream>>>(x, ln1g, ln1b, hbuf);
    gemm_bt<E_DIM, 128, false, false, true><<<(BL / 128) * 12, 512, 0, stream>>>(
        hbuf, wqkvT, qkvb, nullptr, qkvB, BL, 3 * E_DIM, 12);
    attn_mfma<<<dim3(32, 32), 256, 0, stream>>>(qkvB, obuf);
    gemm_bt<E_DIM, 128, true, false, false><<<(BL / 128) * 4, 512, 0, stream>>>(
        obuf, woutT, outb, x, x2, BL, E_DIM, 4);
    ln_kernel<<<BL / 4, 256, 0, stream>>>(x2, ln2g, ln2b, h2);
    gemm_bt<E_DIM, 256, false, true, true><<<(BL / 128) * 8, 512, 0, stream>>>(
        h2, w1T, b1, nullptr, g1, BL, HID_DIM, 8);
    gemm_bt<HID_DIM, 128, true, false, false><<<(BL / 128) * 4, 512, 0, stream>>>(
        g1, w2T, b2, x2, outp, BL, E_DIM, 4);
}